// Round 1
// baseline (90.202 us; speedup 1.0000x reference)
//
#include <hip/hip_runtime.h>
#include <math.h>

#define BB 32
#define CC 1024
#define NN 4096
#define NCH 16          // n-chunks per row
#define CHK 256         // points per chunk

typedef unsigned long long u64;

// Monotone float encoding: key order == (value asc, smaller index wins ties via
// larger (4095-idx)). All finite floats map to mono > 0.
__device__ __forceinline__ u64 enc_key(float v, int gidx) {
    unsigned u = __float_as_uint(v);
    unsigned mono = (u & 0x80000000u) ? ~u : (u | 0x80000000u);
    return ((u64)mono << 12) | (unsigned)(4095 - gidx);
}

// ---------------------------------------------------------------------------
// K1: per-(b,chunk) partial argmax over 1024 channels + copy of the x chunk.
// CHANGE vs prev round: 512 threads/block (2 channels/thread) -> 16 waves/CU
// (was 8) to hide the L1-broadcast load latency of the wave-uniform x reads.
// fp contraction bit-identical to prior verified rounds.
// grid = 32*16 = 512 blocks x 512 threads.
// ---------------------------------------------------------------------------
__global__ __launch_bounds__(512, 4) void k1_argmax_partial(
    const float* __restrict__ x, const float* __restrict__ W,
    float* __restrict__ out_x, u64* __restrict__ pkeys) {
    const int bid = blockIdx.x;
    const int b = bid >> 4, k = bid & 15;
    const int tid = threadIdx.x;

    if (tid < 192) {
        int d = tid >> 6;
        int off = (tid & 63) << 2;
        const size_t p = (size_t)(b * 3 + d) * NN + k * CHK + off;
        *(float4*)(out_x + p) = *(const float4*)(x + p);
    }

    float w0[2], w1[2], w2[2];
    #pragma unroll
    for (int q = 0; q < 2; ++q) {
        int c = q * 512 + tid;
        w0[q] = W[c * 3 + 0];
        w1[q] = W[c * 3 + 1];
        w2[q] = W[c * 3 + 2];
    }

    const float* xb = x + (size_t)b * 3 * NN + k * CHK;
    float best[2] = {-INFINITY, -INFINITY};
    int gn[2] = {0, 0};

    #pragma unroll 2
    for (int n = 0; n < CHK; n += 4) {
        float4 a0 = *(const float4*)(xb + n);
        float4 a1 = *(const float4*)(xb + NN + n);
        float4 a2 = *(const float4*)(xb + 2 * NN + n);
        #pragma unroll
        for (int q = 0; q < 2; ++q) {
            // identical fp contraction to verified rounds (bit-matched ref)
            float v0 = fmaf(w2[q], a2.x, fmaf(w1[q], a1.x, w0[q] * a0.x));
            float v1 = fmaf(w2[q], a2.y, fmaf(w1[q], a1.y, w0[q] * a0.y));
            float v2 = fmaf(w2[q], a2.z, fmaf(w1[q], a1.z, w0[q] * a0.z));
            float v3 = fmaf(w2[q], a2.w, fmaf(w1[q], a1.w, w0[q] * a0.w));
            float gm = fmaxf(fmaxf(v0, v1), fmaxf(v2, v3));   // exact
            if (gm > best[q]) { best[q] = gm; gn[q] = n; }    // first group wins
        }
    }

    #pragma unroll
    for (int q = 0; q < 2; ++q) {
        int n = gn[q];
        float4 a0 = *(const float4*)(xb + n);
        float4 a1 = *(const float4*)(xb + NN + n);
        float4 a2 = *(const float4*)(xb + 2 * NN + n);
        float v0 = fmaf(w2[q], a2.x, fmaf(w1[q], a1.x, w0[q] * a0.x));
        float v1 = fmaf(w2[q], a2.y, fmaf(w1[q], a1.y, w0[q] * a0.y));
        float v2 = fmaf(w2[q], a2.z, fmaf(w1[q], a1.z, w0[q] * a0.z));
        int j = (v0 == best[q]) ? 0 : (v1 == best[q]) ? 1 : (v2 == best[q]) ? 2 : 3;
        pkeys[(size_t)(b * NCH + k) * CC + q * 512 + tid] =
            enc_key(best[q], k * CHK + n + j);
    }
}

// ---------------------------------------------------------------------------
// K2: per-row mega-kernel incl. placement. grid = 32 blocks x 1024 threads.
// CHANGES vs prev round:
//  (1) the 16 pkeys loads are hoisted into registers BEFORE the LDS-zero
//      phase so their ~900-cycle HBM/L3 latency hides under the zeroing.
//  (2) imp2 placement scatters into a 16 KB LDS staging buffer; the global
//      write becomes one coalesced float4 pass (was 4096 scattered 4B stores
//      per row). LDS total ~102 KB (< 160 KB; grid is 32 so occupancy of the
//      remaining CUs is moot).
// All arithmetic unchanged (bit-exact).
// ---------------------------------------------------------------------------
__global__ __launch_bounds__(1024) void k2_row_all(
    const u64* __restrict__ pkeys, float* __restrict__ counts,
    float* __restrict__ imp2, float* __restrict__ ent) {
    __shared__ int   cnt[NN];               // 16 KB: counts per point
    __shared__ int   H[NCH * (CC + 1)];     // 65.6 KB: hist -> chunk-prefix/cursor
    __shared__ int   exvs[CC + 1];          // 4.1 KB: exclusive value prefix
    __shared__ float imp2s[NN];             // 16 KB: staged imp2 row
    __shared__ int   wsum[16];
    __shared__ float esum[16];

    const int b = blockIdx.x;
    const int tid = threadIdx.x;
    const int wv = tid >> 6, lane = tid & 63;

    // 0. issue the 16 partial-key loads NOW (latency hides under LDS zeroing)
    u64 kr[NCH];
    {
        const u64* pk = pkeys + (size_t)b * NCH * CC + tid;
        #pragma unroll
        for (int k = 0; k < NCH; ++k) kr[k] = pk[k * CC];
    }

    // 1. zero
    #pragma unroll
    for (int i = 0; i < 4; ++i) cnt[tid + i * 1024] = 0;
    #pragma unroll
    for (int i = 0; i < 16; ++i) H[tid + i * 1024] = 0;   // 16384 of 16400
    if (tid < NCH * (CC + 1) - 16 * 1024) H[16 * 1024 + tid] = 0;
    __syncthreads();

    // 2. combine 16 partial keys for channel c = tid -> winner -> LDS hist
    {
        u64 bestk = 0;
        #pragma unroll
        for (int k = 0; k < NCH; ++k)
            bestk = (kr[k] > bestk) ? kr[k] : bestk;
        int idx = 4095 - (int)(bestk & 0xFFFu);
        atomicAdd(&cnt[idx], 1);
    }
    __syncthreads();

    // 3. write counts (coalesced float4) + per-chunk hist (wave w <-> chunk w)
    {
        float4 cf;
        cf.x = (float)cnt[4 * tid + 0];
        cf.y = (float)cnt[4 * tid + 1];
        cf.z = (float)cnt[4 * tid + 2];
        cf.w = (float)cnt[4 * tid + 3];
        *(float4*)(counts + (size_t)b * NN + 4 * tid) = cf;

        int h0 = 0, h1 = 0;
        #pragma unroll
        for (int r = 0; r < 4; ++r) {
            int ci = cnt[wv * CHK + r * 64 + lane];
            u64 m0 = __ballot(ci == 0);
            u64 m1 = __ballot(ci == 1);
            if (lane == 0) { h0 += (int)__popcll(m0); h1 += (int)__popcll(m1); }
            if (ci > 1) atomicAdd(&H[wv * (CC + 1) + ci], 1);
        }
        if (lane == 0) {           // bins 0/1 never touched by the atomics
            H[wv * (CC + 1) + 0] = h0;
            H[wv * (CC + 1) + 1] = h1;
        }
    }
    __syncthreads();

    // 4. transform H[w][v] -> prefix over chunks (per value v=tid); row total
    //    g_v; entropy partial; wave-level shuffle scan + reduce (no barriers)
    int g_v, run1024 = 0;
    {
        int run = 0;
        #pragma unroll
        for (int w = 0; w < NCH; ++w) {
            int t = H[w * (CC + 1) + tid];
            H[w * (CC + 1) + tid] = run;     // prefix of chunks < w
            run += t;
        }
        g_v = run;
        if (tid == 0) {                      // value bin 1024 handled by thread 0
            int run2 = 0;
            #pragma unroll
            for (int w = 0; w < NCH; ++w) {
                int t = H[w * (CC + 1) + CC];
                H[w * (CC + 1) + CC] = run2;
                run2 += t;
            }
            run1024 = run2;
        }
    }
    const float S = 1024.0f + 4096.0f * 1e-6f;   // sum(counts)+N*eps exactly
    float e = 0.f;
    if (g_v) {
        float p = ((float)tid + 1e-6f) / S;
        e = (float)g_v * p * log2f(p);
    }
    if (tid == 0 && run1024) {
        float p = (1024.0f + 1e-6f) / S;
        e += (float)run1024 * p * log2f(p);
    }
    int incl = g_v;                              // wave inclusive scan
    #pragma unroll
    for (int d = 1; d < 64; d <<= 1) {
        int t = __shfl_up(incl, d, 64);
        if (lane >= d) incl += t;
    }
    float er = e;                                // wave entropy reduce
    #pragma unroll
    for (int d = 32; d > 0; d >>= 1)
        er += __shfl_down(er, d, 64);
    if (lane == 63) wsum[wv] = incl;
    if (lane == 0)  esum[wv] = er;
    __syncthreads();

    // 5. wave0: exclusive scan of 16 wave sums; wave1: entropy total -> ent[b]
    if (wv == 0) {
        int v = (lane < 16) ? wsum[lane] : 0;
        int inc2 = v;
        #pragma unroll
        for (int d = 1; d < 16; d <<= 1) {
            int t = __shfl_up(inc2, d, 64);
            if (lane >= d) inc2 += t;
        }
        if (lane < 16) wsum[lane] = inc2 - v;    // exclusive wave prefix
    } else if (wv == 1) {
        float v = (lane < 16) ? esum[lane] : 0.f;
        #pragma unroll
        for (int d = 8; d > 0; d >>= 1)
            v += __shfl_down(v, d, 64);
        if (lane == 0) ent[b] = -v / 12.0f;      // log2(4096) = 12
    }
    __syncthreads();

    // 6. exclusive value prefix -> LDS
    exvs[tid] = incl - g_v + wsum[wv];
    if (tid == 0) exvs[CC] = NN - run1024;
    __syncthreads();

    // 7. stable placement into LDS staging: wave w <-> chunk w; 4 batches of
    //    64 points in index order. Rank among equals within batch via ballot
    //    match-any; rank across batches via per-(chunk,value) cursor in H.
    {
        const u64 ltmask = (1ull << lane) - 1ull;
        int* curw = &H[wv * (CC + 1)];
        for (int r = 0; r < 4; ++r) {
            const int n = wv * CHK + r * 64 + lane;
            const int ci = cnt[n];
            // match-any: eq = mask of lanes whose ci equals mine
            u64 eq = 0, todo = ~0ull;
            while (true) {                        // ~#distinct values iterations
                int src = (int)__builtin_ctzll(todo);
                int v0 = __shfl(ci, src, 64);
                u64 m = __ballot(ci == v0);
                if (ci == v0) eq = m;
                todo &= ~m;
                if (todo == 0ull) break;
            }
            int rank = (int)__popcll(eq & ltmask);
            int c0 = curw[ci];                    // broadcast-ish LDS read
            imp2s[c0 + exvs[ci] + rank] = (float)n;
            if ((eq >> lane) == 1ull)             // highest equal lane updates
                curw[ci] = c0 + (int)__popcll(eq);
        }
    }
    __syncthreads();

    // 8. coalesced float4 write of the staged imp2 row
    {
        float4 f;
        f.x = imp2s[4 * tid + 0];
        f.y = imp2s[4 * tid + 1];
        f.z = imp2s[4 * tid + 2];
        f.w = imp2s[4 * tid + 3];
        *(float4*)(imp2 + (size_t)b * NN + 4 * tid) = f;
    }
}

extern "C" void kernel_launch(void* const* d_in, const int* in_sizes, int n_in,
                              void* d_out, int out_size, void* d_ws, size_t ws_size,
                              hipStream_t stream) {
    const float* x = (const float*)d_in[0];    // [32,3,4096]
    const float* W = (const float*)d_in[1];    // [1024,3]
    float* out    = (float*)d_out;
    float* out_x  = out;                        // 393216
    float* counts = out + (size_t)BB * 3 * NN;  // 131072
    float* imp2   = counts + (size_t)BB * NN;   // 131072
    float* ent    = imp2 + (size_t)BB * NN;     // 32

    u64* pkeys = (u64*)d_ws;                    // 32*16*1024 u64 = 4 MB

    k1_argmax_partial<<<BB * NCH, 512, 0, stream>>>(x, W, out_x, pkeys);
    k2_row_all<<<BB, 1024, 0, stream>>>(pkeys, counts, imp2, ent);
}

// Round 2
// 81.209 us; speedup vs baseline: 1.1107x; 1.1107x over previous
//
#include <hip/hip_runtime.h>
#include <math.h>

#define BB 32
#define CC 1024
#define NN 4096
#define NCH 16          // n-chunks per row
#define CHK 256         // points per chunk

typedef unsigned long long u64;

// Monotone float encoding: key order == (value asc, smaller index wins ties via
// larger (4095-idx)). All finite floats map to mono > 0.
__device__ __forceinline__ u64 enc_key(float v, int gidx) {
    unsigned u = __float_as_uint(v);
    unsigned mono = (u & 0x80000000u) ? ~u : (u | 0x80000000u);
    return ((u64)mono << 12) | (unsigned)(4095 - gidx);
}

// ---------------------------------------------------------------------------
// K1: per-(b,chunk) partial argmax over 1024 channels (4 per thread) + copy of
// the x chunk to out_x. Wave-uniform x addresses -> scalar/L1-broadcast loads.
// Group-of-4 max trick; winner position resolved by bit-exact recompute.
// grid = 32*16 = 512 blocks x 256 threads.
// REVERTED to the verified round-0 configuration (256 threads, 4 ch/thread):
// the 512-thread variant doubled uniform-load issue for no VALU gain.
// ---------------------------------------------------------------------------
__global__ __launch_bounds__(256) void k1_argmax_partial(
    const float* __restrict__ x, const float* __restrict__ W,
    float* __restrict__ out_x, u64* __restrict__ pkeys) {
    const int bid = blockIdx.x;
    const int b = bid >> 4, k = bid & 15;
    const int tid = threadIdx.x;

    if (tid < 192) {
        int d = tid >> 6;
        int off = (tid & 63) << 2;
        const size_t p = (size_t)(b * 3 + d) * NN + k * CHK + off;
        *(float4*)(out_x + p) = *(const float4*)(x + p);
    }

    float w0[4], w1[4], w2[4];
    #pragma unroll
    for (int q = 0; q < 4; ++q) {
        int c = q * 256 + tid;
        w0[q] = W[c * 3 + 0];
        w1[q] = W[c * 3 + 1];
        w2[q] = W[c * 3 + 2];
    }

    const float* xb = x + (size_t)b * 3 * NN + k * CHK;
    float best[4] = {-INFINITY, -INFINITY, -INFINITY, -INFINITY};
    int gn[4] = {0, 0, 0, 0};

    #pragma unroll 4
    for (int n = 0; n < CHK; n += 4) {
        float4 a0 = *(const float4*)(xb + n);
        float4 a1 = *(const float4*)(xb + NN + n);
        float4 a2 = *(const float4*)(xb + 2 * NN + n);
        #pragma unroll
        for (int q = 0; q < 4; ++q) {
            // identical fp contraction to rounds 1-3 (bit-matched reference)
            float v0 = fmaf(w2[q], a2.x, fmaf(w1[q], a1.x, w0[q] * a0.x));
            float v1 = fmaf(w2[q], a2.y, fmaf(w1[q], a1.y, w0[q] * a0.y));
            float v2 = fmaf(w2[q], a2.z, fmaf(w1[q], a1.z, w0[q] * a0.z));
            float v3 = fmaf(w2[q], a2.w, fmaf(w1[q], a1.w, w0[q] * a0.w));
            float gm = fmaxf(fmaxf(v0, v1), fmaxf(v2, v3));   // exact
            if (gm > best[q]) { best[q] = gm; gn[q] = n; }    // first group wins
        }
    }

    #pragma unroll
    for (int q = 0; q < 4; ++q) {
        int n = gn[q];
        float4 a0 = *(const float4*)(xb + n);
        float4 a1 = *(const float4*)(xb + NN + n);
        float4 a2 = *(const float4*)(xb + 2 * NN + n);
        float v0 = fmaf(w2[q], a2.x, fmaf(w1[q], a1.x, w0[q] * a0.x));
        float v1 = fmaf(w2[q], a2.y, fmaf(w1[q], a1.y, w0[q] * a0.y));
        float v2 = fmaf(w2[q], a2.z, fmaf(w1[q], a1.z, w0[q] * a0.z));
        int j = (v0 == best[q]) ? 0 : (v1 == best[q]) ? 1 : (v2 == best[q]) ? 2 : 3;
        pkeys[(size_t)(b * NCH + k) * CC + q * 256 + tid] =
            enc_key(best[q], k * CHK + n + j);
    }
}

// ---------------------------------------------------------------------------
// K2: per-row mega-kernel incl. placement. grid = 32 blocks x 1024 threads.
// Identical to verified round-0 EXCEPT one isolated change: the imp2
// placement scatters into a 16 KB LDS staging buffer (imp2s) and the global
// write becomes one coalesced pass (stride-1024 read-out -> conflict-free
// LDS banks + fully coalesced dword stores). No register-pressure change.
// ---------------------------------------------------------------------------
__global__ __launch_bounds__(1024) void k2_row_all(
    const u64* __restrict__ pkeys, float* __restrict__ counts,
    float* __restrict__ imp2, float* __restrict__ ent) {
    __shared__ int   cnt[NN];               // 16 KB: counts per point
    __shared__ int   H[NCH * (CC + 1)];     // 65.6 KB: hist -> chunk-prefix/cursor
    __shared__ int   exvs[CC + 1];          // 4.1 KB: exclusive value prefix
    __shared__ float imp2s[NN];             // 16 KB: staged imp2 row
    __shared__ int   wsum[16];
    __shared__ float esum[16];

    const int b = blockIdx.x;
    const int tid = threadIdx.x;
    const int wv = tid >> 6, lane = tid & 63;

    // 1. zero
    #pragma unroll
    for (int i = 0; i < 4; ++i) cnt[tid + i * 1024] = 0;
    #pragma unroll
    for (int i = 0; i < 16; ++i) H[tid + i * 1024] = 0;   // 16384 of 16400
    if (tid < NCH * (CC + 1) - 16 * 1024) H[16 * 1024 + tid] = 0;
    __syncthreads();

    // 2. combine 16 partial keys for channel c = tid -> winner -> LDS hist
    {
        u64 bestk = 0;
        const u64* pk = pkeys + (size_t)b * NCH * CC + tid;
        #pragma unroll
        for (int k = 0; k < NCH; ++k) {
            u64 key = pk[k * CC];
            bestk = (key > bestk) ? key : bestk;
        }
        int idx = 4095 - (int)(bestk & 0xFFFu);
        atomicAdd(&cnt[idx], 1);
    }
    __syncthreads();

    // 3. write counts (coalesced float4) + per-chunk hist (wave w <-> chunk w)
    {
        float4 cf;
        cf.x = (float)cnt[4 * tid + 0];
        cf.y = (float)cnt[4 * tid + 1];
        cf.z = (float)cnt[4 * tid + 2];
        cf.w = (float)cnt[4 * tid + 3];
        *(float4*)(counts + (size_t)b * NN + 4 * tid) = cf;

        int h0 = 0, h1 = 0;
        #pragma unroll
        for (int r = 0; r < 4; ++r) {
            int ci = cnt[wv * CHK + r * 64 + lane];
            u64 m0 = __ballot(ci == 0);
            u64 m1 = __ballot(ci == 1);
            if (lane == 0) { h0 += (int)__popcll(m0); h1 += (int)__popcll(m1); }
            if (ci > 1) atomicAdd(&H[wv * (CC + 1) + ci], 1);
        }
        if (lane == 0) {           // bins 0/1 never touched by the atomics
            H[wv * (CC + 1) + 0] = h0;
            H[wv * (CC + 1) + 1] = h1;
        }
    }
    __syncthreads();

    // 4. transform H[w][v] -> prefix over chunks (per value v=tid); row total
    //    g_v; entropy partial; wave-level shuffle scan + reduce (no barriers)
    int g_v, run1024 = 0;
    {
        int run = 0;
        #pragma unroll
        for (int w = 0; w < NCH; ++w) {
            int t = H[w * (CC + 1) + tid];
            H[w * (CC + 1) + tid] = run;     // prefix of chunks < w
            run += t;
        }
        g_v = run;
        if (tid == 0) {                      // value bin 1024 handled by thread 0
            int run2 = 0;
            #pragma unroll
            for (int w = 0; w < NCH; ++w) {
                int t = H[w * (CC + 1) + CC];
                H[w * (CC + 1) + CC] = run2;
                run2 += t;
            }
            run1024 = run2;
        }
    }
    const float S = 1024.0f + 4096.0f * 1e-6f;   // sum(counts)+N*eps exactly
    float e = 0.f;
    if (g_v) {
        float p = ((float)tid + 1e-6f) / S;
        e = (float)g_v * p * log2f(p);
    }
    if (tid == 0 && run1024) {
        float p = (1024.0f + 1e-6f) / S;
        e += (float)run1024 * p * log2f(p);
    }
    int incl = g_v;                              // wave inclusive scan
    #pragma unroll
    for (int d = 1; d < 64; d <<= 1) {
        int t = __shfl_up(incl, d, 64);
        if (lane >= d) incl += t;
    }
    float er = e;                                // wave entropy reduce
    #pragma unroll
    for (int d = 32; d > 0; d >>= 1)
        er += __shfl_down(er, d, 64);
    if (lane == 63) wsum[wv] = incl;
    if (lane == 0)  esum[wv] = er;
    __syncthreads();

    // 5. wave0: exclusive scan of 16 wave sums; wave1: entropy total -> ent[b]
    if (wv == 0) {
        int v = (lane < 16) ? wsum[lane] : 0;
        int inc2 = v;
        #pragma unroll
        for (int d = 1; d < 16; d <<= 1) {
            int t = __shfl_up(inc2, d, 64);
            if (lane >= d) inc2 += t;
        }
        if (lane < 16) wsum[lane] = inc2 - v;    // exclusive wave prefix
    } else if (wv == 1) {
        float v = (lane < 16) ? esum[lane] : 0.f;
        #pragma unroll
        for (int d = 8; d > 0; d >>= 1)
            v += __shfl_down(v, d, 64);
        if (lane == 0) ent[b] = -v / 12.0f;      // log2(4096) = 12
    }
    __syncthreads();

    // 6. exclusive value prefix -> LDS
    exvs[tid] = incl - g_v + wsum[wv];
    if (tid == 0) exvs[CC] = NN - run1024;
    __syncthreads();

    // 7. stable placement into LDS staging: wave w <-> chunk w; 4 batches of
    //    64 points in index order. Rank among equals within batch via ballot
    //    match-any; rank across batches via per-(chunk,value) cursor in H.
    {
        const u64 ltmask = (1ull << lane) - 1ull;
        int* curw = &H[wv * (CC + 1)];
        for (int r = 0; r < 4; ++r) {
            const int n = wv * CHK + r * 64 + lane;
            const int ci = cnt[n];
            // match-any: eq = mask of lanes whose ci equals mine
            u64 eq = 0, todo = ~0ull;
            while (true) {                        // ~#distinct values iterations
                int src = (int)__builtin_ctzll(todo);
                int v0 = __shfl(ci, src, 64);
                u64 m = __ballot(ci == v0);
                if (ci == v0) eq = m;
                todo &= ~m;
                if (todo == 0ull) break;
            }
            int rank = (int)__popcll(eq & ltmask);
            int c0 = curw[ci];                    // broadcast-ish LDS read
            imp2s[c0 + exvs[ci] + rank] = (float)n;
            if ((eq >> lane) == 1ull)             // highest equal lane updates
                curw[ci] = c0 + (int)__popcll(eq);
        }
    }
    __syncthreads();

    // 8. coalesced write of the staged imp2 row. Stride-1024 read-out:
    //    consecutive lanes -> consecutive LDS banks (conflict-free) and
    //    fully-coalesced global dword stores.
    {
        float* orow = imp2 + (size_t)b * NN;
        #pragma unroll
        for (int i = 0; i < 4; ++i)
            orow[tid + i * 1024] = imp2s[tid + i * 1024];
    }
}

extern "C" void kernel_launch(void* const* d_in, const int* in_sizes, int n_in,
                              void* d_out, int out_size, void* d_ws, size_t ws_size,
                              hipStream_t stream) {
    const float* x = (const float*)d_in[0];    // [32,3,4096]
    const float* W = (const float*)d_in[1];    // [1024,3]
    float* out    = (float*)d_out;
    float* out_x  = out;                        // 393216
    float* counts = out + (size_t)BB * 3 * NN;  // 131072
    float* imp2   = counts + (size_t)BB * NN;   // 131072
    float* ent    = imp2 + (size_t)BB * NN;     // 32

    u64* pkeys = (u64*)d_ws;                    // 32*16*1024 u64 = 4 MB

    k1_argmax_partial<<<BB * NCH, 256, 0, stream>>>(x, W, out_x, pkeys);
    k2_row_all<<<BB, 1024, 0, stream>>>(pkeys, counts, imp2, ent);
}